// Round 13
// baseline (323.249 us; speedup 1.0000x reference)
//
#include <hip/hip_runtime.h>
#include <hip/hip_bf16.h>
#include <stdint.h>

#define T_TOK 4096
#define DM    1024
#define DF    2048
#define NE    8
#define RROWS 8192          // T_TOK * 2
#define BM    128
#define BK    64
#define MAXT  72            // max M-tiles: 8192/128 + 8 partials
#define NG1   (MAXT * (DF / 128))   // 1152 gemm1 blocks
#define NG2   (MAXT * (DM / 128))   // 576 gemm2 blocks

typedef __attribute__((ext_vector_type(8))) short bf16x8;
typedef __attribute__((ext_vector_type(4))) float f32x4;

static __device__ __forceinline__ unsigned short f2bf(float f) {
  union { float f; unsigned u; } v; v.f = f;
  unsigned r = v.u + 0x7fffu + ((v.u >> 16) & 1u);
  return (unsigned short)(r >> 16);
}

// v_cvt_pk_bf16_f32: RNE-packs two f32 into one u32 of 2 bf16 (lo=src0, hi=src1)
static __device__ __forceinline__ unsigned cvtpk(float lo, float hi) {
  unsigned r;
  asm("v_cvt_pk_bf16_f32 %0, %1, %2" : "=v"(r) : "v"(lo), "v"(hi));
  return r;
}

static __device__ __forceinline__ void glds16(const void* g, void* l) {
  __builtin_amdgcn_global_load_lds(
      (__attribute__((address_space(1))) void*)(g),
      (__attribute__((address_space(3))) void*)(l), 16, 0, 0);
}

// read one bf16x8 B-frag from an f32 LDS tile (row stride 256B, XOR-16 swizzle)
static __device__ __forceinline__ bf16x8 ldsBf(const char* base, int rf, int kbyte) {
  int sw = (rf & 15) << 4;
  f32x4 v0 = *(const f32x4*)(base + rf * 256 + (kbyte ^ sw));
  f32x4 v1 = *(const f32x4*)(base + rf * 256 + ((kbyte + 16) ^ sw));
  union { unsigned u[4]; bf16x8 v; } o;
  o.u[0] = cvtpk(v0.x, v0.y);
  o.u[1] = cvtpk(v0.z, v0.w);
  o.u[2] = cvtpk(v1.x, v1.y);
  o.u[3] = cvtpk(v1.z, v1.w);
  return o.v;
}

// ---------------- router: logits, softmax, top-2, x->bf16, block partials ----
__global__ __launch_bounds__(256) void router_kernel(
    const float* __restrict__ x, const float* __restrict__ gw,
    unsigned short* __restrict__ xb,
    int* __restrict__ topk_idx, float* __restrict__ topk_w,
    int* __restrict__ pc, float* __restrict__ pp) {
  __shared__ int lc[8];
  __shared__ float lp[8];
  int wave = threadIdx.x >> 6;
  int lane = threadIdx.x & 63;
  if (threadIdx.x < 8) { lc[threadIdx.x] = 0; lp[threadIdx.x] = 0.f; }
  __syncthreads();

  int t = blockIdx.x * 4 + wave;     // T_TOK = 4096 = 1024*4

  const float4* xp = (const float4*)(x + (size_t)t * DM);
  float4 xv[4];
#pragma unroll
  for (int q = 0; q < 4; ++q) xv[q] = xp[lane + 64 * q];

  ushort4* xbp = (ushort4*)(xb + (size_t)t * DM);
#pragma unroll
  for (int q = 0; q < 4; ++q) {
    ushort4 u;
    u.x = f2bf(xv[q].x); u.y = f2bf(xv[q].y); u.z = f2bf(xv[q].z); u.w = f2bf(xv[q].w);
    xbp[lane + 64 * q] = u;
  }

  float l[NE];
#pragma unroll
  for (int e = 0; e < NE; ++e) {
    const float4* gp = (const float4*)(gw + (size_t)e * DM);
    float s = 0.f;
#pragma unroll
    for (int q = 0; q < 4; ++q) {
      float4 g4 = gp[lane + 64 * q];
      s += xv[q].x * g4.x + xv[q].y * g4.y + xv[q].z * g4.z + xv[q].w * g4.w;
    }
#pragma unroll
    for (int off = 32; off > 0; off >>= 1) s += __shfl_xor(s, off);
    l[e] = s;
  }

  float m = l[0];
#pragma unroll
  for (int e = 1; e < NE; ++e) m = fmaxf(m, l[e]);
  float p[NE], ps = 0.f;
#pragma unroll
  for (int e = 0; e < NE; ++e) { p[e] = expf(l[e] - m); ps += p[e]; }

  int i1 = 0; float v1 = l[0];
#pragma unroll
  for (int e = 1; e < NE; ++e) if (l[e] > v1) { v1 = l[e]; i1 = e; }
  int i2 = -1; float v2 = -1e30f;
#pragma unroll
  for (int e = 0; e < NE; ++e) if (e != i1 && l[e] > v2) { v2 = l[e]; i2 = e; }

  float r2 = expf(v2 - v1);
  float inv12 = 1.f / (1.f + r2);

  if (lane == 0) {
    topk_idx[t * 2] = i1; topk_idx[t * 2 + 1] = i2;
    topk_w[t * 2] = inv12; topk_w[t * 2 + 1] = r2 * inv12;
    atomicAdd(&lc[i1], 1);
    atomicAdd(&lc[i2], 1);
    float inv = 1.f / ps;
#pragma unroll
    for (int e = 0; e < NE; ++e) atomicAdd(&lp[e], p[e] * inv);
  }
  __syncthreads();
  if (threadIdx.x < 8) {
    pc[blockIdx.x * 8 + threadIdx.x] = lc[threadIdx.x];
    pp[blockIdx.x * 8 + threadIdx.x] = lp[threadIdx.x];
  }
}

// ======== fused: reduce partials -> counts + aux + tile descriptors ========
__global__ __launch_bounds__(512) void reduce_build_kernel(
    const int* __restrict__ pc, const float* __restrict__ pp,
    int* __restrict__ counts, float* __restrict__ out_aux,
    int* __restrict__ offsets, int* __restrict__ tiledesc, int* __restrict__ ntiles) {
  __shared__ int sc[8];
  __shared__ float sp[8];
  int wave = threadIdx.x >> 6;      // = expert
  int lane = threadIdx.x & 63;
  int c = 0; float p = 0.f;
#pragma unroll
  for (int j = 0; j < 16; ++j) {
    int idx = lane + 64 * j;        // block index 0..1023
    c += pc[idx * 8 + wave];
    p += pp[idx * 8 + wave];
  }
#pragma unroll
  for (int off = 32; off > 0; off >>= 1) {
    c += __shfl_xor(c, off);
    p += __shfl_xor(p, off);
  }
  if (lane == 0) { sc[wave] = c; sp[wave] = p; counts[wave] = c; }
  __syncthreads();
  if (threadIdx.x == 0) {
    float s = 0.f;
#pragma unroll
    for (int e = 0; e < NE; ++e)
      s += (sp[e] / (float)T_TOK) * ((float)sc[e] / (float)(T_TOK * 2));
    *out_aux = s * (float)NE;

    int off = 0, nt = 0;
    for (int e = 0; e < NE; ++e) {
      offsets[e] = off;
      int n = sc[e];
      for (int r0 = 0; r0 < n; r0 += BM) {
        int rem = n - r0;
        tiledesc[nt * 3 + 0] = e;
        tiledesc[nt * 3 + 1] = off + r0;
        tiledesc[nt * 3 + 2] = rem < BM ? rem : BM;
        ++nt;
      }
      off += n;
    }
    offsets[NE] = off;
    *ntiles = nt;
  }
}

// ---------------- scatter tokens into expert buckets (block-aggregated) ----
__global__ __launch_bounds__(256) void scatter_kernel(
    const int* __restrict__ topk_idx, const float* __restrict__ topk_w,
    const int* __restrict__ offsets, int* __restrict__ fill,
    int* __restrict__ btok, float* __restrict__ bw) {
  __shared__ int lcnt[8], lbase[8];
  int i = blockIdx.x * 256 + threadIdx.x;   // RROWS = 32*256 exactly
  if (threadIdx.x < 8) lcnt[threadIdx.x] = 0;
  __syncthreads();
  int e = topk_idx[i];
  int pos = atomicAdd(&lcnt[e], 1);
  __syncthreads();
  if (threadIdx.x < 8) lbase[threadIdx.x] = atomicAdd(&fill[threadIdx.x], lcnt[threadIdx.x]);
  __syncthreads();
  int j = offsets[e] + lbase[e] + pos;
  btok[j] = i >> 1;
  bw[j] = topk_w[i];
}

// ==== GEMM1, f32 weights direct: h=Xe*W1^T, v=Xe*W3^T, Y=silu(h)*v ====
// A: bf16 LDS (16 KB). B1/B3: raw f32 LDS tiles (32 KB each) staged via glds16,
// converted to bf16 fragments at read time via v_cvt_pk_bf16_f32 (RNE).
__global__ __launch_bounds__(512) void gemm1_kernel(
    const unsigned short* __restrict__ xb,    // [T][DM] bf16
    const float* __restrict__ w1p, const float* __restrict__ w3p, // [NE][DF][DM] f32
    unsigned short* __restrict__ Y,           // [(R+128)][DF] bf16
    const int* __restrict__ btok,
    const int* __restrict__ tiledesc, const int* __restrict__ ntiles) {
  int flat = blockIdx.x;
  int nid = (flat & 7) * (NG1 >> 3) + (flat >> 3);   // XCD-chunked swizzle
  int mt = nid % MAXT;
  int fb = nid / MAXT;

  if (mt >= *ntiles) return;
  int e    = tiledesc[mt * 3 + 0];
  int row0 = tiledesc[mt * 3 + 1];
  int mcnt = tiledesc[mt * 3 + 2];
  int f0   = fb * 128;

  __shared__ __align__(16) unsigned short sA[128 * 64];   // 16 KB bf16
  __shared__ __align__(16) float sB1f[128 * 64];          // 32 KB f32
  __shared__ __align__(16) float sB3f[128 * 64];          // 32 KB f32

  int tid = threadIdx.x;
  int w = tid >> 6, lane = tid & 63;
  int wm = w >> 2, wn = w & 3;

  // A staging (bf16, unchanged)
  int rA0 = w * 8 + (lane >> 3);
  int rA1 = rA0 + 64;
  int colb = (((lane & 7) ^ (lane >> 3)) << 4);
  int tok0 = btok[row0 + ((rA0 < mcnt) ? rA0 : 0)];
  int tok1 = btok[row0 + ((rA1 < mcnt) ? rA1 : 0)];

  // B staging (f32): per round R, wave covers rows R*32 + w*4 + (lane>>4),
  // 16 lanes per row; source col pre-swizzled by XOR-16 on row.
  int r0w = w * 4 + (lane >> 4);                       // 0..31
  int colbB = (((lane & 15) ^ (r0w & 15)) << 4);       // pre-swizzled col bytes

  const char* xbc = (const char*)xb;
  const char* w1c = (const char*)w1p;
  const char* w3c = (const char*)w3p;

  f32x4 acch[4][2] = {};
  f32x4 accv[4][2] = {};

  for (int k0 = 0; k0 < DM; k0 += BK) {
    __syncthreads();
    glds16(xbc + (((size_t)tok0 * DM + k0) * 2) + colb, (char*)sA + w * 1024);
    glds16(xbc + (((size_t)tok1 * DM + k0) * 2) + colb, (char*)sA + (w + 8) * 1024);
#pragma unroll
    for (int R = 0; R < 4; ++R) {
      int r = R * 32 + r0w;                            // r&15 == r0w&15 (R*32%16==0)
      size_t gb = ((size_t)(e * DF + f0 + r) * DM + k0) * 4 + colbB;
      glds16(w1c + gb, (char*)sB1f + R * 8192 + w * 1024);
      glds16(w3c + gb, (char*)sB3f + R * 8192 + w * 1024);
    }
    __syncthreads();

#pragma unroll
    for (int kk = 0; kk < 2; ++kk) {
      int kbA = ((lane >> 4) << 4) + kk * 64;          // bf16 bytes
      int kbB = (lane >> 4) * 32 + kk * 128;           // f32 bytes
      bf16x8 a[4], b1[2], b3[2];
#pragma unroll
      for (int m = 0; m < 4; ++m) {
        int r = wm * 64 + m * 16 + (lane & 15);
        a[m] = *(const bf16x8*)((const char*)sA + r * 128 + (kbA ^ ((r & 7) << 4)));
      }
#pragma unroll
      for (int n = 0; n < 2; ++n) {
        int rf = wn * 32 + n * 16 + (lane & 15);
        b1[n] = ldsBf((const char*)sB1f, rf, kbB);
        b3[n] = ldsBf((const char*)sB3f, rf, kbB);
      }
#pragma unroll
      for (int m = 0; m < 4; ++m)
#pragma unroll
        for (int n = 0; n < 2; ++n) {
          acch[m][n] = __builtin_amdgcn_mfma_f32_16x16x32_bf16(a[m], b1[n], acch[m][n], 0, 0, 0);
          accv[m][n] = __builtin_amdgcn_mfma_f32_16x16x32_bf16(a[m], b3[n], accv[m][n], 0, 0, 0);
        }
    }
  }

  // epilogue: y = silu(h)*v -> bf16 Y
#pragma unroll
  for (int m = 0; m < 4; ++m) {
#pragma unroll
    for (int j = 0; j < 4; ++j) {
      int rl = wm * 64 + m * 16 + (lane >> 4) * 4 + j;
      if (rl < mcnt) {
        size_t yrow = (size_t)(row0 + rl) * DF + f0;
#pragma unroll
        for (int n = 0; n < 2; ++n) {
          float h = acch[m][n][j], v = accv[m][n][j];
          float y = (h / (1.f + expf(-h))) * v;
          Y[yrow + wn * 32 + n * 16 + (lane & 15)] = f2bf(y);
        }
      }
    }
  }
}

// ==== GEMM2, f32 w2 direct: out[tok] += w * (Y * W2^T) ====
__global__ __launch_bounds__(512) void gemm2_kernel(
    const unsigned short* __restrict__ Y,     // [(R+128)][DF] bf16
    const float* __restrict__ w2p,            // [NE][DM][DF] f32
    float* __restrict__ out,
    const int* __restrict__ btok, const float* __restrict__ bw,
    const int* __restrict__ tiledesc, const int* __restrict__ ntiles) {
  int flat = blockIdx.y * MAXT + blockIdx.x;
  int nid = (flat & 7) * (NG2 >> 3) + (flat >> 3);
  int mt = nid % MAXT;
  int cb = nid / MAXT;

  if (mt >= *ntiles) return;
  int e    = tiledesc[mt * 3 + 0];
  int row0 = tiledesc[mt * 3 + 1];
  int mcnt = tiledesc[mt * 3 + 2];
  int c0   = cb * 128;

  __shared__ __align__(16) unsigned short sA[128 * 64];   // 16 KB bf16
  __shared__ __align__(16) float sBf[128 * 64];           // 32 KB f32

  int tid = threadIdx.x;
  int w = tid >> 6, lane = tid & 63;
  int wm = w >> 2, wn = w & 3;

  int rA0 = w * 8 + (lane >> 3);
  int rA1 = rA0 + 64;
  int colb = (((lane & 7) ^ (lane >> 3)) << 4);

  int r0w = w * 4 + (lane >> 4);
  int colbB = (((lane & 15) ^ (r0w & 15)) << 4);

  const char* yc  = (const char*)Y;
  const char* w2c = (const char*)w2p;

  f32x4 acc[4][2] = {};

  for (int k0 = 0; k0 < DF; k0 += BK) {
    __syncthreads();
    glds16(yc + (((size_t)(row0 + rA0) * DF + k0) * 2) + colb, (char*)sA + w * 1024);
    glds16(yc + (((size_t)(row0 + rA1) * DF + k0) * 2) + colb, (char*)sA + (w + 8) * 1024);
#pragma unroll
    for (int R = 0; R < 4; ++R) {
      int r = R * 32 + r0w;
      size_t gb = ((size_t)(e * DM + c0 + r) * DF + k0) * 4 + colbB;
      glds16(w2c + gb, (char*)sBf + R * 8192 + w * 1024);
    }
    __syncthreads();

#pragma unroll
    for (int kk = 0; kk < 2; ++kk) {
      int kbA = ((lane >> 4) << 4) + kk * 64;
      int kbB = (lane >> 4) * 32 + kk * 128;
      bf16x8 a[4], b[2];
#pragma unroll
      for (int m = 0; m < 4; ++m) {
        int r = wm * 64 + m * 16 + (lane & 15);
        a[m] = *(const bf16x8*)((const char*)sA + r * 128 + (kbA ^ ((r & 7) << 4)));
      }
#pragma unroll
      for (int n = 0; n < 2; ++n) {
        int rf = wn * 32 + n * 16 + (lane & 15);
        b[n] = ldsBf((const char*)sBf, rf, kbB);
      }
#pragma unroll
      for (int m = 0; m < 4; ++m)
#pragma unroll
        for (int n = 0; n < 2; ++n)
          acc[m][n] = __builtin_amdgcn_mfma_f32_16x16x32_bf16(a[m], b[n], acc[m][n], 0, 0, 0);
    }
  }

#pragma unroll
  for (int m = 0; m < 4; ++m) {
#pragma unroll
    for (int j = 0; j < 4; ++j) {
      int rl = wm * 64 + m * 16 + (lane >> 4) * 4 + j;
      if (rl < mcnt) {
        int tok = btok[row0 + rl];
        float wgt = bw[row0 + rl];
#pragma unroll
        for (int n = 0; n < 2; ++n) {
          int col = c0 + wn * 32 + n * 16 + (lane & 15);
          atomicAdd(&out[(size_t)tok * DM + col], wgt * acc[m][n][j]);
        }
      }
    }
  }
}

extern "C" void kernel_launch(void* const* d_in, const int* in_sizes, int n_in,
                              void* d_out, int out_size, void* d_ws, size_t ws_size,
                              hipStream_t stream) {
  const float* x  = (const float*)d_in[0];
  const float* gw = (const float*)d_in[1];
  const float* w1 = (const float*)d_in[2];
  const float* w3 = (const float*)d_in[3];
  const float* w2 = (const float*)d_in[4];
  float* out = (float*)d_out;

  char* ws = (char*)d_ws;
  size_t o = 0;
  auto alloc = [&](size_t b) { size_t r = o; o = (o + b + 255) & ~(size_t)255; return r; };
  size_t o_tidx = alloc((size_t)RROWS * 4);
  size_t o_tw   = alloc((size_t)RROWS * 4);
  size_t o_meta = alloc(4096);
  size_t o_desc = alloc((size_t)MAXT * 3 * 4);
  size_t o_btok = alloc((size_t)RROWS * 4);
  size_t o_bw   = alloc((size_t)RROWS * 4);
  size_t o_pc   = alloc((size_t)1024 * 8 * 4);
  size_t o_pp   = alloc((size_t)1024 * 8 * 4);
  size_t o_xb   = alloc((size_t)T_TOK * DM * 2);
  size_t o_Y    = alloc((size_t)(RROWS + 128) * DF * 2);

  int* tidx   = (int*)(ws + o_tidx);
  float* tw   = (float*)(ws + o_tw);
  int* meta   = (int*)(ws + o_meta);
  int* counts = meta;
  int* fill   = meta + 8;
  int* offs   = meta + 16;
  int* ntiles = meta + 25;
  int* desc   = (int*)(ws + o_desc);
  int* btok   = (int*)(ws + o_btok);
  float* bw   = (float*)(ws + o_bw);
  int* pc     = (int*)(ws + o_pc);
  float* pp   = (float*)(ws + o_pp);
  unsigned short* xb = (unsigned short*)(ws + o_xb);
  unsigned short* Y  = (unsigned short*)(ws + o_Y);

  hipMemsetAsync(ws + o_meta, 0, 256, stream);
  hipMemsetAsync(d_out, 0, (size_t)T_TOK * DM * 4, stream);

  router_kernel<<<T_TOK / 4, 256, 0, stream>>>(x, gw, xb, tidx, tw, pc, pp);

  reduce_build_kernel<<<1, 512, 0, stream>>>(
      pc, pp, counts, out + (size_t)T_TOK * DM, offs, desc, ntiles);

  scatter_kernel<<<RROWS / 256, 256, 0, stream>>>(tidx, tw, offs, fill, btok, bw);

  gemm1_kernel<<<NG1, 512, 0, stream>>>(xb, w1, w3, Y, btok, desc, ntiles);
  gemm2_kernel<<<dim3(MAXT, DM / 128), 512, 0, stream>>>(
      Y, w2, out, btok, bw, desc, ntiles);
}

// Round 14
// 244.045 us; speedup vs baseline: 1.3245x; 1.3245x over previous
//
#include <hip/hip_runtime.h>
#include <hip/hip_bf16.h>
#include <stdint.h>

#define T_TOK 4096
#define DM    1024
#define DF    2048
#define NE    8
#define RROWS 8192          // T_TOK * 2
#define BM    128
#define BK    64
#define MAXT  72            // max M-tiles: 8192/128 + 8 partials
#define NG1   (MAXT * (DF / 128))   // 1152 gemm1 blocks
#define CVTB  2048                  // w2-cvt tail blocks in gemm1 grid

typedef __attribute__((ext_vector_type(8))) short bf16x8;
typedef __attribute__((ext_vector_type(4))) float f32x4;

static __device__ __forceinline__ unsigned short f2bf(float f) {
  union { float f; unsigned u; } v; v.f = f;
  unsigned r = v.u + 0x7fffu + ((v.u >> 16) & 1u);
  return (unsigned short)(r >> 16);
}

static __device__ __forceinline__ void glds16(const void* g, void* l) {
  __builtin_amdgcn_global_load_lds(
      (__attribute__((address_space(1))) void*)(g),
      (__attribute__((address_space(3))) void*)(l), 16, 0, 0);
}

// ======== fused: router (blocks 0..1023) + w1/w3 cvt (blocks 1024..5119) ====
// cvt: 8 NT loads issued up-front (MLP), then cvt + 16B bf16x8 stores.
__global__ __launch_bounds__(256) void router_cvt_kernel(
    const float* __restrict__ x, const float* __restrict__ gw,
    unsigned short* __restrict__ xb,
    int* __restrict__ topk_idx, float* __restrict__ topk_w,
    int* __restrict__ pc, float* __restrict__ pp,
    const float* __restrict__ w1, const float* __restrict__ w3,
    unsigned short* __restrict__ d1, unsigned short* __restrict__ d3, int full) {
  __shared__ int lc[8];
  __shared__ float lp[8];
  int bid = blockIdx.x;

  if (bid >= 1024) {                 // ---- cvt part (w1, w3)
    if (!full) return;
    int b = bid - 1024;              // 0..4095
    const float* src = (b >> 11) ? w3 : w1;
    unsigned short* dst = (b >> 11) ? d3 : d1;
    const f32x4* s4 = (const f32x4*)src;
    bf16x8* d8 = (bf16x8*)dst;
    int i = (b & 2047) * 256 + threadIdx.x;   // ushort8 index, 2M total per tensor
    const int stride = 2048 * 256;
    f32x4 f[8];
#pragma unroll
    for (int it = 0; it < 4; ++it) {          // 8 independent NT loads in flight
      size_t base = 2 * (size_t)(i + it * stride);
      f[2 * it]     = __builtin_nontemporal_load(s4 + base);
      f[2 * it + 1] = __builtin_nontemporal_load(s4 + base + 1);
    }
#pragma unroll
    for (int it = 0; it < 4; ++it) {
      union { unsigned short u[8]; bf16x8 v; } o;
      f32x4 a = f[2 * it], c = f[2 * it + 1];
      o.u[0] = f2bf(a.x); o.u[1] = f2bf(a.y); o.u[2] = f2bf(a.z); o.u[3] = f2bf(a.w);
      o.u[4] = f2bf(c.x); o.u[5] = f2bf(c.y); o.u[6] = f2bf(c.z); o.u[7] = f2bf(c.w);
      d8[i + it * stride] = o.v;
    }
    return;
  }

  // ---- router part
  int wave = threadIdx.x >> 6;
  int lane = threadIdx.x & 63;
  if (threadIdx.x < 8) { lc[threadIdx.x] = 0; lp[threadIdx.x] = 0.f; }
  __syncthreads();

  int t = bid * 4 + wave;            // T_TOK = 4096 = 1024*4

  const float4* xp = (const float4*)(x + (size_t)t * DM);
  float4 xv[4];
#pragma unroll
  for (int q = 0; q < 4; ++q) xv[q] = xp[lane + 64 * q];

  ushort4* xbp = (ushort4*)(xb + (size_t)t * DM);
#pragma unroll
  for (int q = 0; q < 4; ++q) {
    ushort4 u;
    u.x = f2bf(xv[q].x); u.y = f2bf(xv[q].y); u.z = f2bf(xv[q].z); u.w = f2bf(xv[q].w);
    xbp[lane + 64 * q] = u;
  }

  float l[NE];
#pragma unroll
  for (int e = 0; e < NE; ++e) {
    const float4* gp = (const float4*)(gw + (size_t)e * DM);
    float s = 0.f;
#pragma unroll
    for (int q = 0; q < 4; ++q) {
      float4 g4 = gp[lane + 64 * q];
      s += xv[q].x * g4.x + xv[q].y * g4.y + xv[q].z * g4.z + xv[q].w * g4.w;
    }
#pragma unroll
    for (int off = 32; off > 0; off >>= 1) s += __shfl_xor(s, off);
    l[e] = s;
  }

  float m = l[0];
#pragma unroll
  for (int e = 1; e < NE; ++e) m = fmaxf(m, l[e]);
  float p[NE], ps = 0.f;
#pragma unroll
  for (int e = 0; e < NE; ++e) { p[e] = expf(l[e] - m); ps += p[e]; }

  int i1 = 0; float v1 = l[0];
#pragma unroll
  for (int e = 1; e < NE; ++e) if (l[e] > v1) { v1 = l[e]; i1 = e; }
  int i2 = -1; float v2 = -1e30f;
#pragma unroll
  for (int e = 0; e < NE; ++e) if (e != i1 && l[e] > v2) { v2 = l[e]; i2 = e; }

  float r2 = expf(v2 - v1);
  float inv12 = 1.f / (1.f + r2);

  if (lane == 0) {
    topk_idx[t * 2] = i1; topk_idx[t * 2 + 1] = i2;
    topk_w[t * 2] = inv12; topk_w[t * 2 + 1] = r2 * inv12;
    atomicAdd(&lc[i1], 1);
    atomicAdd(&lc[i2], 1);
    float inv = 1.f / ps;
#pragma unroll
    for (int e = 0; e < NE; ++e) atomicAdd(&lp[e], p[e] * inv);
  }
  __syncthreads();
  if (threadIdx.x < 8) {
    pc[bid * 8 + threadIdx.x] = lc[threadIdx.x];
    pp[bid * 8 + threadIdx.x] = lp[threadIdx.x];
  }
}

// ======== fused: reduce partials -> counts + aux + tile descriptors ========
__global__ __launch_bounds__(512) void reduce_build_kernel(
    const int* __restrict__ pc, const float* __restrict__ pp,
    int* __restrict__ counts, float* __restrict__ out_aux,
    int* __restrict__ offsets, int* __restrict__ tiledesc, int* __restrict__ ntiles) {
  __shared__ int sc[8];
  __shared__ float sp[8];
  int wave = threadIdx.x >> 6;      // = expert
  int lane = threadIdx.x & 63;
  int c = 0; float p = 0.f;
#pragma unroll
  for (int j = 0; j < 16; ++j) {
    int idx = lane + 64 * j;        // block index 0..1023
    c += pc[idx * 8 + wave];
    p += pp[idx * 8 + wave];
  }
#pragma unroll
  for (int off = 32; off > 0; off >>= 1) {
    c += __shfl_xor(c, off);
    p += __shfl_xor(p, off);
  }
  if (lane == 0) { sc[wave] = c; sp[wave] = p; counts[wave] = c; }
  __syncthreads();
  if (threadIdx.x == 0) {
    float s = 0.f;
#pragma unroll
    for (int e = 0; e < NE; ++e)
      s += (sp[e] / (float)T_TOK) * ((float)sc[e] / (float)(T_TOK * 2));
    *out_aux = s * (float)NE;

    int off = 0, nt = 0;
    for (int e = 0; e < NE; ++e) {
      offsets[e] = off;
      int n = sc[e];
      for (int r0 = 0; r0 < n; r0 += BM) {
        int rem = n - r0;
        tiledesc[nt * 3 + 0] = e;
        tiledesc[nt * 3 + 1] = off + r0;
        tiledesc[nt * 3 + 2] = rem < BM ? rem : BM;
        ++nt;
      }
      off += n;
    }
    offsets[NE] = off;
    *ntiles = nt;
  }
}

// ---------------- scatter tokens into expert buckets (block-aggregated) ----
__global__ __launch_bounds__(256) void scatter_kernel(
    const int* __restrict__ topk_idx, const float* __restrict__ topk_w,
    const int* __restrict__ offsets, int* __restrict__ fill,
    int* __restrict__ btok, float* __restrict__ bw) {
  __shared__ int lcnt[8], lbase[8];
  int i = blockIdx.x * 256 + threadIdx.x;   // RROWS = 32*256 exactly
  if (threadIdx.x < 8) lcnt[threadIdx.x] = 0;
  __syncthreads();
  int e = topk_idx[i];
  int pos = atomicAdd(&lcnt[e], 1);
  __syncthreads();
  if (threadIdx.x < 8) lbase[threadIdx.x] = atomicAdd(&fill[threadIdx.x], lcnt[threadIdx.x]);
  __syncthreads();
  int j = offsets[e] + lbase[e] + pos;
  btok[j] = i >> 1;
  bw[j] = topk_w[i];
}

// ======== GEMM1 + w2-cvt TAIL: blocks [0,NG1) gemm, [NG1,NG1+CVTB) w2 cvt ====
// Tail placement: all gemm blocks obtain CU slots before any cvt block (in-order
// dispatch); cvt overlaps the gemm drain. NT loads keep w2 f32 out of L3.
template <bool WB16, bool CVT>
__global__ __launch_bounds__(512) void gemm1_kernel(
    const unsigned short* __restrict__ xb,    // [T][DM] bf16
    const void* __restrict__ w1p, const void* __restrict__ w3p, // [NE][DF][DM]
    unsigned short* __restrict__ Y,           // [(R+128)][DF] bf16
    const int* __restrict__ btok,
    const int* __restrict__ tiledesc, const int* __restrict__ ntiles,
    const float* __restrict__ w2src, unsigned short* __restrict__ w2dst) {
  int flat = blockIdx.x;

  if (CVT && flat >= NG1) {          // ---- w2 f32->bf16 tail blocks
    int cb = flat - NG1;             // 0..2047
    const f32x4* s4 = (const f32x4*)w2src;
    bf16x8* d8 = (bf16x8*)w2dst;
    int i = cb * 512 + threadIdx.x;  // ushort8 index; 2M total
    const int stride = CVTB * 512;   // 1048576
    f32x4 f[4];
#pragma unroll
    for (int it = 0; it < 2; ++it) {
      size_t base = 2 * (size_t)(i + it * stride);
      f[2 * it]     = __builtin_nontemporal_load(s4 + base);
      f[2 * it + 1] = __builtin_nontemporal_load(s4 + base + 1);
    }
#pragma unroll
    for (int it = 0; it < 2; ++it) {
      union { unsigned short u[8]; bf16x8 v; } o;
      f32x4 a = f[2 * it], c = f[2 * it + 1];
      o.u[0] = f2bf(a.x); o.u[1] = f2bf(a.y); o.u[2] = f2bf(a.z); o.u[3] = f2bf(a.w);
      o.u[4] = f2bf(c.x); o.u[5] = f2bf(c.y); o.u[6] = f2bf(c.z); o.u[7] = f2bf(c.w);
      d8[i + it * stride] = o.v;
    }
    return;
  }

  int nid = (flat & 7) * (NG1 >> 3) + (flat >> 3);   // XCD-chunked swizzle
  int mt = nid % MAXT;
  int fb = nid / MAXT;

  if (mt >= *ntiles) return;
  int e    = tiledesc[mt * 3 + 0];
  int row0 = tiledesc[mt * 3 + 1];
  int mcnt = tiledesc[mt * 3 + 2];
  int f0   = fb * 128;

  __shared__ __align__(16) unsigned short sA[128 * 64];
  __shared__ __align__(16) unsigned short sB1[128 * 64];
  __shared__ __align__(16) unsigned short sB3[128 * 64];

  int tid = threadIdx.x;
  int w = tid >> 6, lane = tid & 63;
  int wm = w >> 2, wn = w & 3;

  int rA0 = w * 8 + (lane >> 3);
  int rA1 = rA0 + 64;
  int colb = (((lane & 7) ^ (lane >> 3)) << 4);   // swizzled source column (bytes)
  int tok0 = btok[row0 + ((rA0 < mcnt) ? rA0 : 0)];
  int tok1 = btok[row0 + ((rA1 < mcnt) ? rA1 : 0)];

  const char* xbc = (const char*)xb;
  const char* w1c = (const char*)w1p;
  const char* w3c = (const char*)w3p;

  f32x4 acch[4][2] = {};
  f32x4 accv[4][2] = {};

  for (int k0 = 0; k0 < DM; k0 += BK) {
    __syncthreads();
    glds16(xbc + (((size_t)tok0 * DM + k0) * 2) + colb, (char*)sA + w * 1024);
    glds16(xbc + (((size_t)tok1 * DM + k0) * 2) + colb, (char*)sA + (w + 8) * 1024);
    if constexpr (WB16) {
      glds16(w1c + (((size_t)(e * DF + f0 + rA0) * DM + k0) * 2) + colb, (char*)sB1 + w * 1024);
      glds16(w1c + (((size_t)(e * DF + f0 + rA1) * DM + k0) * 2) + colb, (char*)sB1 + (w + 8) * 1024);
      glds16(w3c + (((size_t)(e * DF + f0 + rA0) * DM + k0) * 2) + colb, (char*)sB3 + w * 1024);
      glds16(w3c + (((size_t)(e * DF + f0 + rA1) * DM + k0) * 2) + colb, (char*)sB3 + (w + 8) * 1024);
    } else {
#pragma unroll
      for (int it = 0; it < 4; ++it) {
        int gidx = tid + it * 512;            // 0..2047
        int r = gidx >> 4;
        int cb8 = (gidx & 15) * 8;            // byte offset within LDS row
        int sw = cb8 ^ ((r & 7) << 4);
        size_t gbyte = (((size_t)(e * DF + f0 + r) * DM + k0) * 4) + (size_t)cb8 * 2;
        float4 f1 = *(const float4*)(w1c + gbyte);
        float4 f3 = *(const float4*)(w3c + gbyte);
        ushort4 u1, u3;
        u1.x = f2bf(f1.x); u1.y = f2bf(f1.y); u1.z = f2bf(f1.z); u1.w = f2bf(f1.w);
        u3.x = f2bf(f3.x); u3.y = f2bf(f3.y); u3.z = f2bf(f3.z); u3.w = f2bf(f3.w);
        *(ushort4*)((char*)sB1 + r * 128 + sw) = u1;
        *(ushort4*)((char*)sB3 + r * 128 + sw) = u3;
      }
    }
    __syncthreads();

#pragma unroll
    for (int kk = 0; kk < 2; ++kk) {
      int kb = ((lane >> 4) << 4) + kk * 64;
      bf16x8 a[4], b1f[2], b3f[2];
#pragma unroll
      for (int m = 0; m < 4; ++m) {
        int r = wm * 64 + m * 16 + (lane & 15);
        a[m] = *(const bf16x8*)((const char*)sA + r * 128 + (kb ^ ((r & 7) << 4)));
      }
#pragma unroll
      for (int n = 0; n < 2; ++n) {
        int rf = wn * 32 + n * 16 + (lane & 15);
        int ob = rf * 128 + (kb ^ ((rf & 7) << 4));
        b1f[n] = *(const bf16x8*)((const char*)sB1 + ob);
        b3f[n] = *(const bf16x8*)((const char*)sB3 + ob);
      }
#pragma unroll
      for (int m = 0; m < 4; ++m)
#pragma unroll
        for (int n = 0; n < 2; ++n) {
          acch[m][n] = __builtin_amdgcn_mfma_f32_16x16x32_bf16(a[m], b1f[n], acch[m][n], 0, 0, 0);
          accv[m][n] = __builtin_amdgcn_mfma_f32_16x16x32_bf16(a[m], b3f[n], accv[m][n], 0, 0, 0);
        }
    }
  }

  // epilogue: y = silu(h)*v -> bf16 Y
#pragma unroll
  for (int m = 0; m < 4; ++m) {
#pragma unroll
    for (int j = 0; j < 4; ++j) {
      int rl = wm * 64 + m * 16 + (lane >> 4) * 4 + j;
      if (rl < mcnt) {
        size_t yrow = (size_t)(row0 + rl) * DF + f0;
#pragma unroll
        for (int n = 0; n < 2; ++n) {
          float h = acch[m][n][j], v = accv[m][n][j];
          float y = (h / (1.f + expf(-h))) * v;
          Y[yrow + wn * 32 + n * 16 + (lane & 15)] = f2bf(y);
        }
      }
    }
  }
}

// ---------------- GEMM2: out[tok] += w * (Y * W2^T) ----------------
template <bool WB16>
__global__ __launch_bounds__(512) void gemm2_kernel(
    const unsigned short* __restrict__ Y,     // [(R+128)][DF]
    const void* __restrict__ w2p,             // [NE][DM][DF]
    float* __restrict__ out,
    const int* __restrict__ btok, const float* __restrict__ bw,
    const int* __restrict__ tiledesc, const int* __restrict__ ntiles) {
  int flat = blockIdx.y * MAXT + blockIdx.x;
  const int total = MAXT * (DM / 128);            // 576, %8==0
  int nid = (flat & 7) * (total >> 3) + (flat >> 3);
  int mt = nid % MAXT;
  int cb = nid / MAXT;

  if (mt >= *ntiles) return;
  int e    = tiledesc[mt * 3 + 0];
  int row0 = tiledesc[mt * 3 + 1];
  int mcnt = tiledesc[mt * 3 + 2];
  int c0   = cb * 128;

  __shared__ __align__(16) unsigned short sA[128 * 64];
  __shared__ __align__(16) unsigned short sB[128 * 64];

  int tid = threadIdx.x;
  int w = tid >> 6, lane = tid & 63;
  int wm = w >> 2, wn = w & 3;

  int rA0 = w * 8 + (lane >> 3);
  int rA1 = rA0 + 64;
  int colb = (((lane & 7) ^ (lane >> 3)) << 4);

  const char* yc  = (const char*)Y;
  const char* w2c = (const char*)w2p;

  f32x4 acc[4][2] = {};

  for (int k0 = 0; k0 < DF; k0 += BK) {
    __syncthreads();
    glds16(yc + (((size_t)(row0 + rA0) * DF + k0) * 2) + colb, (char*)sA + w * 1024);
    glds16(yc + (((size_t)(row0 + rA1) * DF + k0) * 2) + colb, (char*)sA + (w + 8) * 1024);
    if constexpr (WB16) {
      glds16(w2c + (((size_t)(e * DM + c0 + rA0) * DF + k0) * 2) + colb, (char*)sB + w * 1024);
      glds16(w2c + (((size_t)(e * DM + c0 + rA1) * DF + k0) * 2) + colb, (char*)sB + (w + 8) * 1024);
    } else {
#pragma unroll
      for (int it = 0; it < 4; ++it) {
        int gidx = tid + it * 512;
        int r = gidx >> 4;
        int cb8 = (gidx & 15) * 8;
        int sw = cb8 ^ ((r & 7) << 4);
        size_t gbyte = (((size_t)(e * DM + c0 + r) * DF + k0) * 4) + (size_t)cb8 * 2;
        float4 f = *(const float4*)(w2c + gbyte);
        ushort4 u;
        u.x = f2bf(f.x); u.y = f2bf(f.y); u.z = f2bf(f.z); u.w = f2bf(f.w);
        *(ushort4*)((char*)sB + r * 128 + sw) = u;
      }
    }
    __syncthreads();

#pragma unroll
    for (int kk = 0; kk < 2; ++kk) {
      int kb = ((lane >> 4) << 4) + kk * 64;
      bf16x8 a[4], b[2];
#pragma unroll
      for (int m = 0; m < 4; ++m) {
        int r = wm * 64 + m * 16 + (lane & 15);
        a[m] = *(const bf16x8*)((const char*)sA + r * 128 + (kb ^ ((r & 7) << 4)));
      }
#pragma unroll
      for (int n = 0; n < 2; ++n) {
        int rf = wn * 32 + n * 16 + (lane & 15);
        b[n] = *(const bf16x8*)((const char*)sB + rf * 128 + (kb ^ ((rf & 7) << 4)));
      }
#pragma unroll
      for (int m = 0; m < 4; ++m)
#pragma unroll
        for (int n = 0; n < 2; ++n)
          acc[m][n] = __builtin_amdgcn_mfma_f32_16x16x32_bf16(a[m], b[n], acc[m][n], 0, 0, 0);
    }
  }

#pragma unroll
  for (int m = 0; m < 4; ++m) {
#pragma unroll
    for (int j = 0; j < 4; ++j) {
      int rl = wm * 64 + m * 16 + (lane >> 4) * 4 + j;
      if (rl < mcnt) {
        int tok = btok[row0 + rl];
        float wgt = bw[row0 + rl];
#pragma unroll
        for (int n = 0; n < 2; ++n) {
          int col = c0 + wn * 32 + n * 16 + (lane & 15);
          atomicAdd(&out[(size_t)tok * DM + col], wgt * acc[m][n][j]);
        }
      }
    }
  }
}

extern "C" void kernel_launch(void* const* d_in, const int* in_sizes, int n_in,
                              void* d_out, int out_size, void* d_ws, size_t ws_size,
                              hipStream_t stream) {
  const float* x  = (const float*)d_in[0];
  const float* gw = (const float*)d_in[1];
  const float* w1 = (const float*)d_in[2];
  const float* w3 = (const float*)d_in[3];
  const float* w2 = (const float*)d_in[4];
  float* out = (float*)d_out;

  char* ws = (char*)d_ws;
  size_t o = 0;
  auto alloc = [&](size_t b) { size_t r = o; o = (o + b + 255) & ~(size_t)255; return r; };
  size_t o_tidx = alloc((size_t)RROWS * 4);
  size_t o_tw   = alloc((size_t)RROWS * 4);
  size_t o_meta = alloc(4096);
  size_t o_desc = alloc((size_t)MAXT * 3 * 4);
  size_t o_btok = alloc((size_t)RROWS * 4);
  size_t o_bw   = alloc((size_t)RROWS * 4);
  size_t o_pc   = alloc((size_t)1024 * 8 * 4);
  size_t o_pp   = alloc((size_t)1024 * 8 * 4);
  size_t o_xb   = alloc((size_t)T_TOK * DM * 2);
  size_t o_Y    = alloc((size_t)(RROWS + 128) * DF * 2);
  size_t o_w1b  = alloc((size_t)NE * DF * DM * 2);
  size_t o_w3b  = alloc((size_t)NE * DF * DM * 2);
  size_t o_w2b  = alloc((size_t)NE * DM * DF * 2);
  size_t need_full = o;
  bool full = ws_size >= need_full;

  int* tidx   = (int*)(ws + o_tidx);
  float* tw   = (float*)(ws + o_tw);
  int* meta   = (int*)(ws + o_meta);
  int* counts = meta;
  int* fill   = meta + 8;
  int* offs   = meta + 16;
  int* ntiles = meta + 25;
  int* desc   = (int*)(ws + o_desc);
  int* btok   = (int*)(ws + o_btok);
  float* bw   = (float*)(ws + o_bw);
  int* pc     = (int*)(ws + o_pc);
  float* pp   = (float*)(ws + o_pp);
  unsigned short* xb  = (unsigned short*)(ws + o_xb);
  unsigned short* Y   = (unsigned short*)(ws + o_Y);
  unsigned short* w1b = (unsigned short*)(ws + o_w1b);
  unsigned short* w3b = (unsigned short*)(ws + o_w3b);
  unsigned short* w2b = (unsigned short*)(ws + o_w2b);

  hipMemsetAsync(ws + o_meta, 0, 256, stream);
  hipMemsetAsync(d_out, 0, (size_t)T_TOK * DM * 4, stream);

  // fused router + w1/w3 conversion (w2 deferred to gemm1 tail)
  router_cvt_kernel<<<full ? (1024 + 4096) : 1024, 256, 0, stream>>>(
      x, gw, xb, tidx, tw, pc, pp, w1, w3, w1b, w3b, full ? 1 : 0);

  reduce_build_kernel<<<1, 512, 0, stream>>>(
      pc, pp, counts, out + (size_t)T_TOK * DM, offs, desc, ntiles);

  scatter_kernel<<<RROWS / 256, 256, 0, stream>>>(tidx, tw, offs, fill, btok, bw);

  if (full) {
    // gemm1 blocks [0,1152) + w2-cvt tail blocks [1152,3200)
    gemm1_kernel<true, true><<<NG1 + CVTB, 512, 0, stream>>>(
        xb, w1b, w3b, Y, btok, desc, ntiles, w2, w2b);
    gemm2_kernel<true><<<dim3(MAXT, DM / 128), 512, 0, stream>>>(
        Y, w2b, out, btok, bw, desc, ntiles);
  } else {
    gemm1_kernel<false, false><<<NG1, 512, 0, stream>>>(
        xb, w1, w3, Y, btok, desc, ntiles, nullptr, nullptr);
    gemm2_kernel<false><<<dim3(MAXT, DM / 128), 512, 0, stream>>>(
        Y, w2, out, btok, bw, desc, ntiles);
  }
}